// Round 13
// baseline (134.962 us; speedup 1.0000x reference)
//
#include <hip/hip_runtime.h>
#include <math.h>

#define C_IN 2048
#define N_EXP 64
#define DELTA  3e-4f      // risky-gap threshold (>=100x expected logit error)
#define DELTA2 1e-3f      // candidate window around v2
#define NTOK 16384

typedef __bf16 bf16x8 __attribute__((ext_vector_type(8)));
typedef float f32x4 __attribute__((ext_vector_type(4)));

__device__ __forceinline__ void cvt_split(float f, ushort& h, ushort& l) {
    uint u = __float_as_uint(f);
    uint hr = (u + (0x7FFFu + ((u >> 16) & 1u))) >> 16;
    h = (ushort)hr;
    float hf = __uint_as_float(hr << 16);
    uint v = __float_as_uint(f - hf);
    l = (ushort)((v + (0x7FFFu + ((v >> 16) & 1u))) >> 16);
}

// W [64][2048] fp32 -> frag-major bf16 hi/lo (verbatim r6 layout, refcheck'd):
// o = (eg*64 + ks)*512 + lane*8 + j <-> e = eg*16+(lane&15), k = ks*32+(lane>>4)*8+j
__global__ void conv_w_kernel(const float* __restrict__ W,
                              ushort* __restrict__ whf, ushort* __restrict__ wlf) {
    const int o = blockIdx.x * 256 + threadIdx.x;   // 0..131071
    const int egks = o >> 9;
    const int lane = (o >> 3) & 63;
    const int j = o & 7;
    const int e = (egks >> 6) * 16 + (lane & 15);
    const int k = (egks & 63) * 32 + (lane >> 4) * 8 + j;
    ushort h, lo;
    cvt_split(W[e * C_IN + k], h, lo);
    whf[o] = h;
    wlf[o] = lo;
}

__device__ __forceinline__ void glds16(const void* g, void* l) {
    __builtin_amdgcn_global_load_lds(
        (const __attribute__((address_space(1))) uint32_t*)g,
        (__attribute__((address_space(3))) uint32_t*)l, 16, 0, 0);
}

__device__ __forceinline__ void cvt8(const float4 a, const float4 b2,
                                     uint4& hv, uint4& lv) {
    ushort h[8], q[8];
    cvt_split(a.x, h[0], q[0]);  cvt_split(a.y, h[1], q[1]);
    cvt_split(a.z, h[2], q[2]);  cvt_split(a.w, h[3], q[3]);
    cvt_split(b2.x, h[4], q[4]); cvt_split(b2.y, h[5], q[5]);
    cvt_split(b2.z, h[6], q[6]); cvt_split(b2.w, h[7], q[7]);
    hv = (uint4){(uint)h[0] | ((uint)h[1] << 16), (uint)h[2] | ((uint)h[3] << 16),
                 (uint)h[4] | ((uint)h[5] << 16), (uint)h[6] | ((uint)h[7] << 16)};
    lv = (uint4){(uint)q[0] | ((uint)q[1] << 16), (uint)q[2] | ((uint)q[3] << 16),
                 (uint)q[4] | ((uint)q[5] << 16), (uint)q[6] | ((uint)q[7] << 16)};
}

// ============ Kernel A: partial logits, MLP-first (no barriers) ============
// Grid 1024 = 512 token-groups x 2 K-halves; 256 thr = 4 INDEPENDENT waves.
// Wave w: 32 tokens x experts [w*16,+16) x K-half [kw*1024,+1024), 16 slices
// of 64 cols. x: direct global->reg, 2 slice-sets (8 float4 each), issued one
// slice ahead behind sched_barrier fences (compiler-counted waits ~vmcnt(12)).
// W: wave-PRIVATE LDS ring-2 via gload_lds (1-KB contiguous frag-major).
// 16 decoupled wave-streams/CU, each holding ~8-12 loads in flight.
__global__ __launch_bounds__(256, 4) void partial_kernel(
    const float* __restrict__ x, const ushort* __restrict__ whf,
    const ushort* __restrict__ wlf, float* __restrict__ part)
{
    __shared__ __align__(16) ushort wlds[4][4096];   // 8 KB/wave: 2 slots x 4 KB

    const int tid = threadIdx.x;
    const int w = tid >> 6, l = tid & 63;
    const int tg = blockIdx.x >> 1, kw = blockIdx.x & 1;
    const int t0 = tg * 32;
    const int tr = l & 15, kg = l >> 4;

    const float* xg = x + (size_t)t0 * C_IN + kw * 1024;
    const float* xr0 = xg + (size_t)tr * C_IN + kg * 8;
    const float* xr1 = xg + (size_t)(tr + 16) * C_IN + kg * 8;
    const ushort* whp = whf + (size_t)(w * 64 + kw * 32) * 512 + l * 8;
    const ushort* wlp = wlf + (size_t)(w * 64 + kw * 32) * 512 + l * 8;
    ushort* wsl = wlds[w];

    f32x4 acc0 = {0.f, 0.f, 0.f, 0.f};
    f32x4 acc1 = {0.f, 0.f, 0.f, 0.f};
    float4 xa[8], xb[8];

    // issue x slice S into register set D (8 independent float4 loads)
#define XISS(D, S) do {                                                       \
    _Pragma("unroll") for (int j_ = 0; j_ < 2; ++j_) {                        \
        (D)[j_ * 4 + 0] = *(const float4*)(xr0 + ((S) * 2 + j_) * 32);        \
        (D)[j_ * 4 + 1] = *(const float4*)(xr0 + ((S) * 2 + j_) * 32 + 4);    \
        (D)[j_ * 4 + 2] = *(const float4*)(xr1 + ((S) * 2 + j_) * 32);        \
        (D)[j_ * 4 + 3] = *(const float4*)(xr1 + ((S) * 2 + j_) * 32 + 4);    \
    }                                                                         \
    __builtin_amdgcn_sched_barrier(0);                                        \
} while (0)

    // issue W slice S (4 x 1-KB gload_lds) into wave-private slot S&1
#define WISS(S) do {                                                          \
    ushort* d_ = wsl + ((S) & 1) * 2048;                                      \
    _Pragma("unroll") for (int j_ = 0; j_ < 2; ++j_) {                        \
        glds16(whp + (size_t)((S) * 2 + j_) * 512, d_ + j_ * 1024);           \
        glds16(wlp + (size_t)((S) * 2 + j_) * 512, d_ + j_ * 1024 + 512);     \
    }                                                                         \
    __builtin_amdgcn_sched_barrier(0);                                        \
} while (0)

    // consume slice S from register set D and W slot S&1 (2 ksteps x 6 MFMA)
#define CONSUME(D, S) do {                                                    \
    _Pragma("unroll") for (int jj_ = 0; jj_ < 2; ++jj_) {                     \
        uint4 h0_, l0_, h1_, l1_;                                             \
        cvt8((D)[jj_ * 4 + 0], (D)[jj_ * 4 + 1], h0_, l0_);                   \
        cvt8((D)[jj_ * 4 + 2], (D)[jj_ * 4 + 3], h1_, l1_);                   \
        uint4 bhu_ = *(const uint4*)&wsl[((S) & 1) * 2048 + jj_ * 1024 + l * 8]; \
        uint4 blu_ = *(const uint4*)&wsl[((S) & 1) * 2048 + jj_ * 1024 + 512 + l * 8]; \
        bf16x8 ah0_ = __builtin_bit_cast(bf16x8, h0_);                        \
        bf16x8 al0_ = __builtin_bit_cast(bf16x8, l0_);                        \
        bf16x8 ah1_ = __builtin_bit_cast(bf16x8, h1_);                        \
        bf16x8 al1_ = __builtin_bit_cast(bf16x8, l1_);                        \
        bf16x8 bh_ = __builtin_bit_cast(bf16x8, bhu_);                        \
        bf16x8 bl_ = __builtin_bit_cast(bf16x8, blu_);                        \
        __builtin_amdgcn_s_setprio(1);                                        \
        acc0 = __builtin_amdgcn_mfma_f32_16x16x32_bf16(ah0_, bh_, acc0, 0, 0, 0); \
        acc1 = __builtin_amdgcn_mfma_f32_16x16x32_bf16(ah1_, bh_, acc1, 0, 0, 0); \
        acc0 = __builtin_amdgcn_mfma_f32_16x16x32_bf16(al0_, bh_, acc0, 0, 0, 0); \
        acc1 = __builtin_amdgcn_mfma_f32_16x16x32_bf16(al1_, bh_, acc1, 0, 0, 0); \
        acc0 = __builtin_amdgcn_mfma_f32_16x16x32_bf16(ah0_, bl_, acc0, 0, 0, 0); \
        acc1 = __builtin_amdgcn_mfma_f32_16x16x32_bf16(ah1_, bl_, acc1, 0, 0, 0); \
        __builtin_amdgcn_s_setprio(0);                                        \
    }                                                                         \
} while (0)

    // prologue: slices 0 (set xa) and 1 (set xb) in flight
    XISS(xa, 0); WISS(0);
    XISS(xb, 1); WISS(1);

#pragma unroll 1
    for (int m = 0; m < 7; ++m) {
        const int s0 = 2 * m;
        CONSUME(xa, s0);
        XISS(xa, s0 + 2); WISS(s0 + 2);
        CONSUME(xb, s0 + 1);
        XISS(xb, s0 + 3); WISS(s0 + 3);
    }
    CONSUME(xa, 14);
    CONSUME(xb, 15);

    // partials: [kw][token][expert] fp32; rows from verified r6 C/D mapping
    float* pp = part + ((size_t)kw * NTOK + t0) * 64 + w * 16;
#pragma unroll
    for (int r = 0; r < 4; ++r) {
        pp[(kg * 4 + r) * 64 + tr] = acc0[r];
        pp[(16 + kg * 4 + r) * 64 + tr] = acc1[r];
    }
#undef XISS
#undef WISS
#undef CONSUME
}

// ============ Kernel B: reduce + softmax + top-2 + fp32 repair ============
__global__ __launch_bounds__(256, 4) void finish_kernel(
    const float* __restrict__ x, const float* __restrict__ Wf,
    const float* __restrict__ b, const float* __restrict__ part,
    float* __restrict__ out)
{
    const int tid = threadIdx.x;
    const int w = tid >> 6, l = tid & 63;
    const int t0 = blockIdx.x * 64;
    const int e = l;
    const float be = b[e];

    for (int ti = 0; ti < 16; ++ti) {
        const int tok = t0 + w * 16 + ti;
        float logit = part[(size_t)tok * 64 + e]
                    + part[(size_t)NTOK * 64 + (size_t)tok * 64 + e] + be;

        float v1, v2, v3; int i1, i2;
        for (int pass = 0; pass < 2; ++pass) {
            v1 = logit; i1 = e;
#pragma unroll
            for (int off = 32; off >= 1; off >>= 1) {
                float ov = __shfl_xor(v1, off, 64);
                int   oi = __shfl_xor(i1, off, 64);
                if (ov > v1 || (ov == v1 && oi < i1)) { v1 = ov; i1 = oi; }
            }
            v2 = (e == i1) ? -3.4e38f : logit;
            i2 = (e == i1) ? N_EXP : e;
#pragma unroll
            for (int off = 32; off >= 1; off >>= 1) {
                float ov = __shfl_xor(v2, off, 64);
                int   oi = __shfl_xor(i2, off, 64);
                if (ov > v2 || (ov == v2 && oi < i2)) { v2 = ov; i2 = oi; }
            }
            v3 = (e == i1 || e == i2) ? -3.4e38f : logit;
#pragma unroll
            for (int off = 32; off >= 1; off >>= 1) {
                float ov = __shfl_xor(v3, off, 64);
                v3 = (ov > v3) ? ov : v3;
            }
            if (pass == 1) break;
            const bool risky = (v1 - v2 < DELTA) || (v2 - v3 < DELTA);
            if (!risky) break;
            // exact fp32 recompute of candidate experts (wave-uniform path)
            unsigned long long cm = __ballot(logit >= v2 - DELTA2);
            const float* xr = x + (size_t)tok * C_IN;
            while (cm) {
                const int ce = __ffsll((unsigned long long)cm) - 1;
                cm &= cm - 1;
                const float* wr = Wf + (size_t)ce * C_IN;
                float p = 0.f;
#pragma unroll 8
                for (int i = 0; i < 32; ++i)
                    p = fmaf(xr[l + 64 * i], wr[l + 64 * i], p);
#pragma unroll
                for (int off = 32; off >= 1; off >>= 1)
                    p += __shfl_xor(p, off, 64);
                if (e == ce) logit = p + be;
            }
        }

        float ex = expf(logit - v1);
        float ssum = ex;
#pragma unroll
        for (int off = 32; off >= 1; off >>= 1)
            ssum += __shfl_xor(ssum, off, 64);
        const float inv = 1.0f / ssum;
        const float p1 = inv;
        const float p2 = expf(v2 - v1) * inv;
        const float o = (e == i1) ? p1 : ((e == i2) ? p2 : 0.0f);
        out[(size_t)tok * N_EXP + e] = o;
    }
}

extern "C" void kernel_launch(void* const* d_in, const int* in_sizes, int n_in,
                              void* d_out, int out_size, void* d_ws, size_t ws_size,
                              hipStream_t stream) {
    const float* x = (const float*)d_in[0];   // [4,4096,2048]
    const float* W = (const float*)d_in[1];   // [64,2048]
    const float* b = (const float*)d_in[2];   // [64]
    float* out = (float*)d_out;               // [4,4096,64]

    ushort* whf = (ushort*)d_ws;              // frag-major bf16 hi, 256 KB
    ushort* wlf = whf + N_EXP * C_IN;         // frag-major bf16 lo, 256 KB
    float* part = (float*)((char*)d_ws + 524288);   // [2][16384][64] fp32, 8 MB

    conv_w_kernel<<<512, 256, 0, stream>>>(W, whf, wlf);
    partial_kernel<<<1024, 256, 0, stream>>>(x, whf, wlf, part);
    finish_kernel<<<256, 256, 0, stream>>>(x, W, b, part, out);
}